// Round 2
// baseline (1005.305 us; speedup 1.0000x reference)
//
#include <hip/hip_runtime.h>
#include <hip/hip_bf16.h>

#define VOCAB 32000
#define CTX   8
#define HDIM  256
#define BATCH 512
#define NOUT  (CTX * VOCAB)   // 256000

typedef __attribute__((ext_vector_type(8))) short short8;
typedef __attribute__((ext_vector_type(4))) float f32x4;

// bf16 h2 staging buffer (256 KB) — device global referenced by symbol from
// both kernels, so kernel_launch needs no runtime API calls at all.
__device__ short g_h2[BATCH * HDIM];

__device__ __forceinline__ short f2bf(float f) {
    __hip_bfloat16 h = __float2bfloat16(f);   // RNE
    return __builtin_bit_cast(short, h);
}

// ---------------------------------------------------------------------------
// Kernel 1: h2 = relu(relu(sum_p E[p, x[b,p], :] + b1) @ W2 + b2)  -> bf16
// grid = BATCH blocks, HDIM threads. Tiny: ~4 MB gather + 67 MFLOP.
// ---------------------------------------------------------------------------
__global__ __launch_bounds__(HDIM) void front_kernel(
    const int* __restrict__ x, const float* __restrict__ E,
    const float* __restrict__ b1, const float* __restrict__ W2,
    const float* __restrict__ b2)
{
    const int b = blockIdx.x;
    const int d = threadIdx.x;

    __shared__ float sh[HDIM];
    __shared__ int   sidx[CTX];
    if (d < CTX) sidx[d] = x[b * CTX + d];
    __syncthreads();

    float acc = b1[d];
#pragma unroll
    for (int p = 0; p < CTX; ++p)
        acc += E[((long)(p * VOCAB + sidx[p])) * HDIM + d];

    sh[d] = fmaxf(acc, 0.f);
    __syncthreads();

    float acc2 = b2[d];
#pragma unroll 8
    for (int k = 0; k < HDIM; ++k)
        acc2 = fmaf(sh[k], W2[k * HDIM + d], acc2);

    g_h2[b * HDIM + d] = f2bf(fmaxf(acc2, 0.f));
}

// ---------------------------------------------------------------------------
// Kernel 2: C[512, 256000] = h2 @ W3 + b3   (bf16 MFMA, fp32 accumulate)
//
// Each wave owns 32 consecutive output columns (NT=2 tiles of 16) and the FULL
// M=512 — so W3 is fetched from HBM exactly once (256 MB). B-fragments (W3
// cols, K=256) are converted to bf16 once and held in registers (64 VGPRs);
// b3 is folded into the accumulator init. A (h2 bf16, 256 KB) is L2-resident
// and read as per-lane 16B fragments directly from global — no LDS/barriers.
//
// Correctness note on MFMA layouts: A and B fragments are built with the SAME
// (kk,krow,j) -> k mapping, so any HW permutation of k-slots cancels in the
// dot product. Only the C/D mapping must be exact: col = lane&15,
// row = (lane>>4)*4 + reg  (m89-verified for 16x16x32_bf16).
//
// W3 loads are nontemporal (read-once, 256 MB) and C stores are nontemporal
// (write-once, 512 MB) so the streaming traffic doesn't evict the hot A
// (256 KB, ~2 GB of re-reads) from L2.
// ---------------------------------------------------------------------------
#define WAVES 4
#define NT    2   // 16-col tiles per wave -> 32 cols/wave, 128 cols/block

__global__ __launch_bounds__(256) void out_kernel(
    const float* __restrict__ W3,  // [HDIM, NOUT] fp32, row-major (n contiguous)
    const float* __restrict__ b3,  // [NOUT]
    float* __restrict__ C)         // [BATCH, NOUT]
{
    const short* A = g_h2;         // [BATCH, HDIM] bf16 (as short)

    const int wave  = threadIdx.x >> 6;
    const int lane  = threadIdx.x & 63;
    const int col16 = lane & 15;
    const int krow  = lane >> 4;   // 0..3
    const long n0   = ((long)blockIdx.x * WAVES + wave) * (NT * 16);

    // --- one-time: load + convert B fragments (W3 cols), and bias ---
    short8 bfrag[NT][8];
    float  bias[NT];
#pragma unroll
    for (int nt = 0; nt < NT; ++nt) {
        const long n = n0 + nt * 16 + col16;
        bias[nt] = b3[n];
#pragma unroll
        for (int kk = 0; kk < 8; ++kk) {
            const float* wp = W3 + (long)(kk * 32 + krow * 8) * NOUT + n;
            short8 t;
#pragma unroll
            for (int j = 0; j < 8; ++j)
                t[j] = f2bf(__builtin_nontemporal_load(wp + (long)j * NOUT));
            bfrag[nt][kk] = t;
        }
    }

    // --- main loop over M tiles: A frags from L2, 16 MFMAs, store ---
    for (int mt = 0; mt < BATCH / 16; ++mt) {
        const short8* ap =
            (const short8*)(A + (mt * 16 + col16) * HDIM + krow * 8);
        short8 afrag[8];
#pragma unroll
        for (int kk = 0; kk < 8; ++kk)
            afrag[kk] = ap[kk * 4];   // stride 32 shorts = 4 * short8

        f32x4 acc[NT];
#pragma unroll
        for (int nt = 0; nt < NT; ++nt)
            acc[nt] = (f32x4){bias[nt], bias[nt], bias[nt], bias[nt]};

#pragma unroll
        for (int kk = 0; kk < 8; ++kk)
#pragma unroll
            for (int nt = 0; nt < NT; ++nt)
                acc[nt] = __builtin_amdgcn_mfma_f32_16x16x32_bf16(
                    afrag[kk], bfrag[nt][kk], acc[nt], 0, 0, 0);

#pragma unroll
        for (int nt = 0; nt < NT; ++nt) {
            const long n = n0 + nt * 16 + col16;
            float* cp = C + (long)(mt * 16 + krow * 4) * NOUT + n;
#pragma unroll
            for (int i = 0; i < 4; ++i)
                __builtin_nontemporal_store(acc[nt][i], cp + (long)i * NOUT);
        }
    }
}

// ---------------------------------------------------------------------------
extern "C" void kernel_launch(void* const* d_in, const int* in_sizes, int n_in,
                              void* d_out, int out_size, void* d_ws, size_t ws_size,
                              hipStream_t stream)
{
    const int*   x  = (const int*)  d_in[0];
    const float* E  = (const float*)d_in[1];
    const float* b1 = (const float*)d_in[2];
    const float* W2 = (const float*)d_in[3];
    const float* b2 = (const float*)d_in[4];
    const float* W3 = (const float*)d_in[5];
    const float* b3 = (const float*)d_in[6];
    float* out = (float*)d_out;

    front_kernel<<<BATCH, HDIM, 0, stream>>>(x, E, b1, W2, b2);
    out_kernel<<<NOUT / (WAVES * NT * 16), 256, 0, stream>>>(W3, b3, out);
}